// Round 11
// baseline (307.132 us; speedup 1.0000x reference)
//
#include <hip/hip_runtime.h>
#include <hip/hip_bf16.h>

#define HW 2304          // 48*48
#define NB 8             // batch
#define NC 256           // input channels
#define HID 128          // heads*dim_head
#define DH 32            // dim_head
#define NH 4             // heads
#define SCALE 0.17677669529663687f   // 1/sqrt(32)
#define LOG2E 1.4426950408889634f
#define LN2   0.6931471805599453f
#define NQT 18           // query tiles (128 q each)
#define KSPL 2           // key split factor
#define KHALF (HW / KSPL)            // 1152 keys per block
#define NIT (KHALF / 64)             // 18 iterations per block

using bf16x8 = __attribute__((ext_vector_type(8))) short;
using f32x4  = __attribute__((ext_vector_type(4))) float;

__device__ __forceinline__ short f2bf(float f) {   // RNE float->bf16
    unsigned u = __float_as_uint(f);
    u += 0x7FFF + ((u >> 16) & 1);
    return (short)(u >> 16);
}
__device__ __forceinline__ unsigned pk2bf(float a, float b) {  // pack 2 bf16 (RNE)
    union { __hip_bfloat162 h; unsigned u; } cv;
    cv.h = __float22bfloat162_rn(float2{a, b});
    return cv.u;
}
__device__ __forceinline__ void gld16(const void* g, void* l) {  // 16B global->LDS DMA
    __builtin_amdgcn_global_load_lds(
        (const __attribute__((address_space(1))) unsigned*)g,
        (__attribute__((address_space(3))) unsigned*)l, 16, 0, 0);
}

// ---------------------------------------------------------------------------
// Fused pre-pass. z<8: x [b][256][2304] fp32 -> Xt [b][2304][256] bf16.
// z==8: weight fp32->bf16 conversion + zero E/tickets/ready flags.
// ---------------------------------------------------------------------------
__global__ __launch_bounds__(256)
void prep(const float* __restrict__ x, const float* __restrict__ wq,
          const float* __restrict__ wo, short* __restrict__ Xt,
          short* __restrict__ Wq, short* __restrict__ Wo, float* __restrict__ wsz)
{
    if (blockIdx.z == 8) {
        const int bid = blockIdx.x + 72 * blockIdx.y;
        if (bid == 0 && threadIdx.x == 0) { wsz[0] = 0.f; ((int*)wsz)[1] = 0; }
        if (bid < 5) {                           // zero 1152 ticket+ready ints
            const int i2 = bid * 256 + threadIdx.x;
            if (i2 < 2 * NQT * 32) ((int*)wsz)[16 + i2] = 0;
        }
        const int i = bid * 256 + threadIdx.x;
        if (i < 384 * 256) Wq[i] = f2bf(wq[i]);
        if (i < 256 * 128) Wo[i] = f2bf(wo[i]);
        return;
    }
    __shared__ float T[32][33];
    const int b = blockIdx.z, c0 = blockIdx.y * 32, s0 = blockIdx.x * 32;
    const int ts = threadIdx.x & 31, tc = threadIdx.x >> 5;
    #pragma unroll
    for (int cc = tc; cc < 32; cc += 8)
        T[cc][ts] = x[((size_t)b * NC + c0 + cc) * HW + s0 + ts];
    __syncthreads();
    const int tcc = threadIdx.x & 31, tss = threadIdx.x >> 5;
    #pragma unroll
    for (int ss = tss; ss < 32; ss += 8)
        Xt[((size_t)b * HW + s0 + ss) * NC + c0 + tcc] = f2bf(T[tcc][ss]);
}

// ---------------------------------------------------------------------------
// MFMA 1x1-conv GEMM with gld16-staged double-buffered LDS tiles (unchanged
// from round 10). Q(xSCALE*LOG2E)/K(pair-permuted) [bh][s][dh], V [bh][dh][s];
// else fp32 out + ticketed energy store.
// ---------------------------------------------------------------------------
template<int KD, bool QKV>
__global__ __launch_bounds__(256, 4)
void conv_mfma(const short* __restrict__ A, const short* __restrict__ Bt,
               const float* __restrict__ bias, float* __restrict__ out0,
               short* __restrict__ Qb, short* __restrict__ Kb,
               short* __restrict__ Vb, float* __restrict__ E,
               int* __restrict__ ticket, int nblocks, float* __restrict__ edst)
{
    const int b  = blockIdx.z;
    const int bm = blockIdx.y * 64;
    const int bn = blockIdx.x * 128;
    const int t  = threadIdx.x;
    const int w  = t >> 6, lane = t & 63;
    const int n16 = lane & 15, quad = lane >> 4;

    __shared__ __align__(16) char csm[24576];   // 2 x (A 4KB | B 8KB)
    __shared__ float red[4];

    const int rL = lane >> 2, cswz = (lane & 3) ^ (rL & 3);
    const char* agl = (const char*)(A  + (size_t)(bm + rL) * KD + cswz * 8);
    const char* bgl = (const char*)(Bt + ((size_t)b * HW + bn + rL) * KD + cswz * 8);

    auto issue = [&](int kc, int pbuf) {
        char* base = csm + pbuf * 12288;
        if (w == 0) {
            gld16(agl + (size_t)(0 * 16 * KD + kc) * 2, base + 0 * 1024);
            gld16(agl + (size_t)(1 * 16 * KD + kc) * 2, base + 1 * 1024);
            gld16(bgl + (size_t)(0 * 16 * KD + kc) * 2, base + 4096 + 0 * 1024);
        } else if (w == 1) {
            gld16(agl + (size_t)(2 * 16 * KD + kc) * 2, base + 2 * 1024);
            gld16(agl + (size_t)(3 * 16 * KD + kc) * 2, base + 3 * 1024);
            gld16(bgl + (size_t)(1 * 16 * KD + kc) * 2, base + 4096 + 1 * 1024);
        } else if (w == 2) {
            gld16(bgl + (size_t)(2 * 16 * KD + kc) * 2, base + 4096 + 2 * 1024);
            gld16(bgl + (size_t)(3 * 16 * KD + kc) * 2, base + 4096 + 3 * 1024);
            gld16(bgl + (size_t)(4 * 16 * KD + kc) * 2, base + 4096 + 4 * 1024);
        } else {
            gld16(bgl + (size_t)(5 * 16 * KD + kc) * 2, base + 4096 + 5 * 1024);
            gld16(bgl + (size_t)(6 * 16 * KD + kc) * 2, base + 4096 + 6 * 1024);
            gld16(bgl + (size_t)(7 * 16 * KD + kc) * 2, base + 4096 + 7 * 1024);
        }
    };

    f32x4 acc[4][2] = {};
    const int rsw = (quad ^ (n16 & 3)) * 16;    // frag-read swizzle (bytes)
    constexpr int NI = KD / 32;

    issue(0, 0);
    for (int ki = 0; ki < NI; ++ki) {
        const int p = ki & 1;
        __syncthreads();
        if (ki + 1 < NI) issue((ki + 1) * 32, p ^ 1);

        const char* Ap = csm + p * 12288;
        const char* Bp = Ap + 4096;
        bf16x8 am[4], bq[2];
        #pragma unroll
        for (int tm = 0; tm < 4; ++tm)
            am[tm] = *(const bf16x8*)(Ap + tm * 1024 + n16 * 64 + rsw);
        #pragma unroll
        for (int j = 0; j < 2; ++j)
            bq[j] = *(const bf16x8*)(Bp + (w * 2 + j) * 1024 + n16 * 64 + rsw);
        #pragma unroll
        for (int tm = 0; tm < 4; ++tm)
            #pragma unroll
            for (int j = 0; j < 2; ++j)
                acc[tm][j] = __builtin_amdgcn_mfma_f32_16x16x32_bf16(am[tm], bq[j], acc[tm][j], 0, 0, 0);
    }

    float e = 0.f;
    #pragma unroll
    for (int tm = 0; tm < 4; ++tm) {
        const int o0 = bm + tm * 16 + quad * 4;
        const float4 bb = *(const float4*)(bias + o0);
        #pragma unroll
        for (int j = 0; j < 2; ++j) {
            const int s = bn + (w * 2 + j) * 16 + n16;
            float v[4] = {acc[tm][j][0] + bb.x, acc[tm][j][1] + bb.y,
                          acc[tm][j][2] + bb.z, acc[tm][j][3] + bb.w};
            e -= 0.5f * (v[0]*v[0] + v[1]*v[1] + v[2]*v[2] + v[3]*v[3]);
            if (QKV) {
                if (o0 < HID) {
                    const int h = o0 >> 5, dh0 = o0 & 31;
                    const float qs = SCALE * LOG2E;
                    short4 pk = {f2bf(v[0]*qs), f2bf(v[1]*qs),
                                 f2bf(v[2]*qs), f2bf(v[3]*qs)};
                    *(short4*)(Qb + ((size_t)(b * NH + h) * HW + s) * DH + dh0) = pk;
                } else if (o0 < 2 * HID) {
                    const int c = o0 - HID, h = c >> 5, dh0 = c & 31;
                    const int g = s & 31;
                    const int sp = (s & ~31) | ((g & 1) << 4) | (g >> 1);
                    short4 pk = {f2bf(v[0]), f2bf(v[1]), f2bf(v[2]), f2bf(v[3])};
                    *(short4*)(Kb + ((size_t)(b * NH + h) * HW + sp) * DH + dh0) = pk;
                } else {
                    const int c = o0 - 2 * HID, h = c >> 5, dh0 = c & 31;
                    #pragma unroll
                    for (int r = 0; r < 4; ++r)
                        Vb[((size_t)(b * NH + h) * DH + dh0 + r) * HW + s] = f2bf(v[r]);
                }
            } else {
                #pragma unroll
                for (int r = 0; r < 4; ++r)
                    out0[((size_t)b * NC + o0 + r) * HW + s] = v[r];
            }
        }
    }

    #pragma unroll
    for (int off = 32; off > 0; off >>= 1) e += __shfl_down(e, off);
    if (lane == 0) red[w] = e;
    __syncthreads();
    if (t == 0) {
        atomicAdd(E, red[0] + red[1] + red[2] + red[3]);
        if (!QKV) {
            __threadfence();
            const int prev = atomicAdd(ticket, 1);
            if (prev == nblocks - 1) {
                __threadfence();
                edst[0] = atomicAdd(E, 0.f);
            }
        }
    }
}

// ---------------------------------------------------------------------------
// Flash attention v8: flash7 structure + 2-way key split (constant total DMA,
// 2x blocks/CU). Grid (36, 32): blockIdx.x = qt*2 + kh. Block = 128 q x 4
// waves, keys [kh*1152, +1152), 18 iterations x 64 keys, shared DMA'd KV
// double buffer, 1 barrier/iteration. m=0 fixed shift => merge = pure add:
// first finisher (device-scope ticket) stores partials (O as bf16 pairs,
// ls/ts fp32) to ws and sets a ready flag; second arrival spins (partner is
// guaranteed resident+ahead -> no deadlock), merges, normalizes, writes attT
// + energy.
// ---------------------------------------------------------------------------
__global__ __launch_bounds__(256)
void flash8(const short* __restrict__ Qb, const short* __restrict__ Kb,
            const short* __restrict__ Vb, short* __restrict__ attT,
            float* __restrict__ E, int* __restrict__ ftk, int* __restrict__ frd,
            char* __restrict__ part)
{
    __shared__ __align__(16) char smem[16384 + 4 * 5120];
    __shared__ int sprev;

    const int qt   = blockIdx.x >> 1, kh = blockIdx.x & 1;
    const int bh   = blockIdx.y;
    const int w    = threadIdx.x >> 6;
    const int lane = threadIdx.x & 63;
    const int n16  = lane & 15, quad = lane >> 4;
    const int qb   = qt * 128 + w * 32;
    const int pidx = bh * NQT + qt;

    bf16x8 aq[2];
    #pragma unroll
    for (int qg = 0; qg < 2; ++qg)
        aq[qg] = *(const bf16x8*)(Qb + ((size_t)bh * HW + qb + qg * 16 + n16) * DH + quad * 8);

    // DMA role: waves 0,1 -> K halves; waves 2,3 -> V halves.
    const int rL = lane >> 2, cL = (lane & 3) ^ (rL & 3);
    const int kbeg = kh * KHALF;
    const char* gbase; size_t gstep;
    if (w < 2) {
        gbase = (const char*)(Kb + ((size_t)bh * HW + kbeg) * DH)
              + ((w & 1) * 16 + rL) * 64 + cL * 16;
        gstep = 2048;                      // 32 keys * 64 B
    } else {
        gbase = (const char*)(Vb + (size_t)bh * DH * HW + kbeg)
              + (size_t)((w & 1) * 16 + rL) * (HW * 2) + cL * 16;
        gstep = 64;                        // 32 keys * 2 B per dh-row
    }

    gld16(gbase,         smem + 0    + w * 1024);   // preload iteration 0
    gld16(gbase + gstep, smem + 4096 + w * 1024);

    f32x4 acc[2][2] = {};
    float ls[2][4] = {}, ts[2][4] = {};
    const int swz = (quad ^ (n16 & 3)) * 8;
    short* Pbase = (short*)(smem + 16384) + w * 2560;

    for (int it = 0; it < NIT; ++it) {
        const int p = it & 1;
        __syncthreads();
        if (it + 1 < NIT) {
            const size_t g0 = (size_t)(2 * it + 2) * gstep;
            gld16(gbase + g0,         smem + (p ^ 1) * 8192 + 0    + w * 1024);
            gld16(gbase + g0 + gstep, smem + (p ^ 1) * 8192 + 4096 + w * 1024);
        }

        #pragma unroll
        for (int ca = 0; ca < 2; ++ca) {
            const short* kb = (const short*)(smem + p * 8192 + ca * 4096);
            short* Ps = Pbase + ca * 1280;
            unsigned* P32 = (unsigned*)Ps;

            const bf16x8 bk0 = *(const bf16x8*)(kb + n16 * 32 + swz);
            const bf16x8 bk1 = *(const bf16x8*)(kb + 512  + n16 * 32 + swz);
            const bf16x8 bv0 = *(const bf16x8*)(kb + 1024 + n16 * 32 + swz);
            const bf16x8 bv1 = *(const bf16x8*)(kb + 1536 + n16 * 32 + swz);

            #pragma unroll
            for (int qg = 0; qg < 2; ++qg) {
                f32x4 z = {};
                const f32x4 s0 = __builtin_amdgcn_mfma_f32_16x16x32_bf16(aq[qg], bk0, z, 0, 0, 0);
                const f32x4 s1 = __builtin_amdgcn_mfma_f32_16x16x32_bf16(aq[qg], bk1, z, 0, 0, 0);
                #pragma unroll
                for (int r = 0; r < 4; ++r) {
                    const float p0 = __builtin_amdgcn_exp2f(s0[r]);
                    const float p1 = __builtin_amdgcn_exp2f(s1[r]);
                    ls[qg][r] += p0 + p1;
                    ts[qg][r] += p0 * s0[r] + p1 * s1[r];
                    P32[(qg * 16 + quad * 4 + r) * 20 + n16] = pk2bf(p0, p1);
                }
            }
            #pragma unroll
            for (int qg = 0; qg < 2; ++qg) {
                const bf16x8 pa = *(const bf16x8*)(Ps + (qg * 16 + n16) * 40 + quad * 8);
                acc[qg][0] = __builtin_amdgcn_mfma_f32_16x16x32_bf16(pa, bv0, acc[qg][0], 0, 0, 0);
                acc[qg][1] = __builtin_amdgcn_mfma_f32_16x16x32_bf16(pa, bv1, acc[qg][1], 0, 0, 0);
            }
        }
    }

    // reduce ls/ts across the 16 key-lanes of each quad group
    #pragma unroll
    for (int m = 1; m < 16; m <<= 1)
        #pragma unroll
        for (int qg = 0; qg < 2; ++qg)
            #pragma unroll
            for (int r = 0; r < 4; ++r) {
                ls[qg][r] += __shfl_xor(ls[qg][r], m);
                ts[qg][r] += __shfl_xor(ts[qg][r], m);
            }

    // ---- key-split merge ----
    char* pb = part + (size_t)pidx * 9216;
    unsigned* O32 = (unsigned*)pb;            // 128 q x 16 (bf16 pairs: dh n16|n16+16)
    float* pls = (float*)(pb + 8192);         // 128
    float* pts = pls + 128;                   // 128

    if (threadIdx.x == 0) sprev = atomicAdd(&ftk[pidx], 1);
    __syncthreads();
    const int prev = sprev;

    if (prev == 0) {                          // first to finish: store partials
        #pragma unroll
        for (int qg = 0; qg < 2; ++qg)
            #pragma unroll
            for (int r = 0; r < 4; ++r) {
                const int ql = w * 32 + qg * 16 + quad * 4 + r;
                O32[ql * 16 + n16] = pk2bf(acc[qg][0][r], acc[qg][1][r]);
                if (n16 == 0) { pls[ql] = ls[qg][r]; pts[ql] = ts[qg][r]; }
            }
        __threadfence();
        __syncthreads();
        if (threadIdx.x == 0) atomicExch(&frd[pidx], 1);
        return;
    }

    // second: wait for partner's partials (partner is resident & ahead)
    if (threadIdx.x == 0) {
        while (atomicCAS(&frd[pidx], 2, 2) != 1) __builtin_amdgcn_s_sleep(8);
    }
    __syncthreads();
    __threadfence();

    const int bb = bh >> 2, h = bh & 3;
    float e = 0.f;
    #pragma unroll
    for (int qg = 0; qg < 2; ++qg)
        #pragma unroll
        for (int r = 0; r < 4; ++r) {
            const int ql = w * 32 + qg * 16 + quad * 4 + r;
            const unsigned u = O32[ql * 16 + n16];
            float a0 = acc[qg][0][r] + __uint_as_float(u << 16);
            float a1 = acc[qg][1][r] + __uint_as_float(u & 0xffff0000u);
            const float L = ls[qg][r] + pls[ql];
            const float T = ts[qg][r] + pts[ql];
            const float invl = 1.f / L;
            const int q = qt * 128 + ql;
            short* ap = attT + ((size_t)bb * HW + q) * HID + h * 32;
            ap[n16]      = f2bf(a0 * invl);
            ap[n16 + 16] = f2bf(a1 * invl);
            e += (LN2 * T) * invl - __logf(L);
        }
    e = (n16 == 0) ? e : 0.f;
    e += __shfl_xor(e, 16);
    e += __shfl_xor(e, 32);
    if (lane == 0) atomicAdd(E, e);
}

// ---------------------------------------------------------------------------
extern "C" void kernel_launch(void* const* d_in, const int* in_sizes, int n_in,
                              void* d_out, int out_size, void* d_ws, size_t ws_size,
                              hipStream_t stream) {
    const float* x     = (const float*)d_in[0];
    const float* w_qkv = (const float*)d_in[1];
    const float* b_qkv = (const float*)d_in[2];
    const float* w_out = (const float*)d_in[3];
    const float* b_out = (const float*)d_in[4];
    float* out = (float*)d_out;

    float* wsf    = (float*)d_ws;
    float* E      = wsf;                               // [0] energy accumulator
    int*   ticket = (int*)d_ws + 1;                    // [1] conv2 ticket
    int*   ftk    = (int*)d_ws + 16;                   // [16..592) flash tickets
    int*   frd    = ftk + NQT * 32;                    // ready flags
    short* Wq   = (short*)(wsf + 1280);                // bf16 [384][256]
    short* Wo   = Wq + 384 * 256;                      // bf16 [256][128]
    short* Xt   = Wo + 256 * 128;                      // bf16 [b][s][c] (9.44 MB)
    short* Qb   = Xt + (size_t)NB * HW * NC;           // bf16 [bh][s][dh] (xSCALE*log2e)
    short* Kb   = Qb + (size_t)NB * NH * HW * DH;      // bf16 [bh][s'][dh], pair-perm
    short* Vb   = Kb + (size_t)NB * NH * HW * DH;      // bf16 [bh][dh][s]
    short* attT = Vb + (size_t)NB * NH * HW * DH;      // bf16 [b][s][hid]
    char*  part = (char*)Xt;                           // partials overlay Xt (5.3 MB)

    prep<<<dim3(HW / 32, NC / 32, NB + 1), 256, 0, stream>>>(
        x, w_qkv, w_out, Xt, Wq, Wo, wsf);
    conv_mfma<NC, true><<<dim3(18, 6, NB), 256, 0, stream>>>(
        Wq, Xt, b_qkv, nullptr, Qb, Kb, Vb, E, nullptr, 0, nullptr);
    flash8<<<dim3(NQT * KSPL, NB * NH), 256, 0, stream>>>(
        Qb, Kb, Vb, attT, E, ftk, frd, part);
    conv_mfma<HID, false><<<dim3(18, 4, NB), 256, 0, stream>>>(
        Wo, attT, b_out, out, nullptr, nullptr, nullptr, E,
        ticket, 18 * 4 * NB, out + (size_t)NB * NC * HW);
}

// Round 12
// 214.568 us; speedup vs baseline: 1.4314x; 1.4314x over previous
//
#include <hip/hip_runtime.h>
#include <hip/hip_bf16.h>

#define HW 2304          // 48*48
#define NB 8             // batch
#define NC 256           // input channels
#define HID 128          // heads*dim_head
#define DH 32            // dim_head
#define NH 4             // heads
#define SCALE 0.17677669529663687f   // 1/sqrt(32)
#define LOG2E 1.4426950408889634f
#define LN2   0.6931471805599453f
#define NQT 18           // query tiles (128 q each)
#define KSPL 2           // key split factor
#define KHALF (HW / KSPL)            // 1152 keys per block
#define NIT (KHALF / 64)             // 18 iterations per block

using bf16x8 = __attribute__((ext_vector_type(8))) short;
using f32x4  = __attribute__((ext_vector_type(4))) float;

__device__ __forceinline__ short f2bf(float f) {   // RNE float->bf16
    unsigned u = __float_as_uint(f);
    u += 0x7FFF + ((u >> 16) & 1);
    return (short)(u >> 16);
}
__device__ __forceinline__ unsigned pk2bf(float a, float b) {  // pack 2 bf16 (RNE)
    union { __hip_bfloat162 h; unsigned u; } cv;
    cv.h = __float22bfloat162_rn(float2{a, b});
    return cv.u;
}
__device__ __forceinline__ void gld16(const void* g, void* l) {  // 16B global->LDS DMA
    __builtin_amdgcn_global_load_lds(
        (const __attribute__((address_space(1))) unsigned*)g,
        (__attribute__((address_space(3))) unsigned*)l, 16, 0, 0);
}

// ---------------------------------------------------------------------------
// Fused pre-pass. z<8: x [b][256][2304] fp32 -> Xt [b][2304][256] bf16.
// z==8: weight fp32->bf16 conversion + zero E/ticket.
// ---------------------------------------------------------------------------
__global__ __launch_bounds__(256)
void prep(const float* __restrict__ x, const float* __restrict__ wq,
          const float* __restrict__ wo, short* __restrict__ Xt,
          short* __restrict__ Wq, short* __restrict__ Wo, float* __restrict__ wsz)
{
    if (blockIdx.z == 8) {
        const int bid = blockIdx.x + 72 * blockIdx.y;
        if (bid == 0 && threadIdx.x == 0) { wsz[0] = 0.f; ((int*)wsz)[1] = 0; }
        const int i = bid * 256 + threadIdx.x;
        if (i < 384 * 256) Wq[i] = f2bf(wq[i]);
        if (i < 256 * 128) Wo[i] = f2bf(wo[i]);
        return;
    }
    __shared__ float T[32][33];
    const int b = blockIdx.z, c0 = blockIdx.y * 32, s0 = blockIdx.x * 32;
    const int ts = threadIdx.x & 31, tc = threadIdx.x >> 5;
    #pragma unroll
    for (int cc = tc; cc < 32; cc += 8)
        T[cc][ts] = x[((size_t)b * NC + c0 + cc) * HW + s0 + ts];
    __syncthreads();
    const int tcc = threadIdx.x & 31, tss = threadIdx.x >> 5;
    #pragma unroll
    for (int ss = tss; ss < 32; ss += 8)
        Xt[((size_t)b * HW + s0 + ss) * NC + c0 + tcc] = f2bf(T[tcc][ss]);
}

// ---------------------------------------------------------------------------
// MFMA 1x1-conv GEMM with gld16-staged double-buffered LDS tiles (unchanged).
// Q(xSCALE*LOG2E)/K(pair-permuted) [bh][s][dh], V [bh][dh][s];
// else fp32 out + ticketed energy store.
// ---------------------------------------------------------------------------
template<int KD, bool QKV>
__global__ __launch_bounds__(256, 4)
void conv_mfma(const short* __restrict__ A, const short* __restrict__ Bt,
               const float* __restrict__ bias, float* __restrict__ out0,
               short* __restrict__ Qb, short* __restrict__ Kb,
               short* __restrict__ Vb, float* __restrict__ E,
               int* __restrict__ ticket, int nblocks, float* __restrict__ edst)
{
    const int b  = blockIdx.z;
    const int bm = blockIdx.y * 64;
    const int bn = blockIdx.x * 128;
    const int t  = threadIdx.x;
    const int w  = t >> 6, lane = t & 63;
    const int n16 = lane & 15, quad = lane >> 4;

    __shared__ __align__(16) char csm[24576];   // 2 x (A 4KB | B 8KB)
    __shared__ float red[4];

    const int rL = lane >> 2, cswz = (lane & 3) ^ (rL & 3);
    const char* agl = (const char*)(A  + (size_t)(bm + rL) * KD + cswz * 8);
    const char* bgl = (const char*)(Bt + ((size_t)b * HW + bn + rL) * KD + cswz * 8);

    auto issue = [&](int kc, int pbuf) {
        char* base = csm + pbuf * 12288;
        if (w == 0) {
            gld16(agl + (size_t)(0 * 16 * KD + kc) * 2, base + 0 * 1024);
            gld16(agl + (size_t)(1 * 16 * KD + kc) * 2, base + 1 * 1024);
            gld16(bgl + (size_t)(0 * 16 * KD + kc) * 2, base + 4096 + 0 * 1024);
        } else if (w == 1) {
            gld16(agl + (size_t)(2 * 16 * KD + kc) * 2, base + 2 * 1024);
            gld16(agl + (size_t)(3 * 16 * KD + kc) * 2, base + 3 * 1024);
            gld16(bgl + (size_t)(1 * 16 * KD + kc) * 2, base + 4096 + 1 * 1024);
        } else if (w == 2) {
            gld16(bgl + (size_t)(2 * 16 * KD + kc) * 2, base + 4096 + 2 * 1024);
            gld16(bgl + (size_t)(3 * 16 * KD + kc) * 2, base + 4096 + 3 * 1024);
            gld16(bgl + (size_t)(4 * 16 * KD + kc) * 2, base + 4096 + 4 * 1024);
        } else {
            gld16(bgl + (size_t)(5 * 16 * KD + kc) * 2, base + 4096 + 5 * 1024);
            gld16(bgl + (size_t)(6 * 16 * KD + kc) * 2, base + 4096 + 6 * 1024);
            gld16(bgl + (size_t)(7 * 16 * KD + kc) * 2, base + 4096 + 7 * 1024);
        }
    };

    f32x4 acc[4][2] = {};
    const int rsw = (quad ^ (n16 & 3)) * 16;    // frag-read swizzle (bytes)
    constexpr int NI = KD / 32;

    issue(0, 0);
    for (int ki = 0; ki < NI; ++ki) {
        const int p = ki & 1;
        __syncthreads();
        if (ki + 1 < NI) issue((ki + 1) * 32, p ^ 1);

        const char* Ap = csm + p * 12288;
        const char* Bp = Ap + 4096;
        bf16x8 am[4], bq[2];
        #pragma unroll
        for (int tm = 0; tm < 4; ++tm)
            am[tm] = *(const bf16x8*)(Ap + tm * 1024 + n16 * 64 + rsw);
        #pragma unroll
        for (int j = 0; j < 2; ++j)
            bq[j] = *(const bf16x8*)(Bp + (w * 2 + j) * 1024 + n16 * 64 + rsw);
        #pragma unroll
        for (int tm = 0; tm < 4; ++tm)
            #pragma unroll
            for (int j = 0; j < 2; ++j)
                acc[tm][j] = __builtin_amdgcn_mfma_f32_16x16x32_bf16(am[tm], bq[j], acc[tm][j], 0, 0, 0);
    }

    float e = 0.f;
    #pragma unroll
    for (int tm = 0; tm < 4; ++tm) {
        const int o0 = bm + tm * 16 + quad * 4;
        const float4 bb = *(const float4*)(bias + o0);
        #pragma unroll
        for (int j = 0; j < 2; ++j) {
            const int s = bn + (w * 2 + j) * 16 + n16;
            float v[4] = {acc[tm][j][0] + bb.x, acc[tm][j][1] + bb.y,
                          acc[tm][j][2] + bb.z, acc[tm][j][3] + bb.w};
            e -= 0.5f * (v[0]*v[0] + v[1]*v[1] + v[2]*v[2] + v[3]*v[3]);
            if (QKV) {
                if (o0 < HID) {
                    const int h = o0 >> 5, dh0 = o0 & 31;
                    const float qs = SCALE * LOG2E;
                    short4 pk = {f2bf(v[0]*qs), f2bf(v[1]*qs),
                                 f2bf(v[2]*qs), f2bf(v[3]*qs)};
                    *(short4*)(Qb + ((size_t)(b * NH + h) * HW + s) * DH + dh0) = pk;
                } else if (o0 < 2 * HID) {
                    const int c = o0 - HID, h = c >> 5, dh0 = c & 31;
                    const int g = s & 31;
                    const int sp = (s & ~31) | ((g & 1) << 4) | (g >> 1);
                    short4 pk = {f2bf(v[0]), f2bf(v[1]), f2bf(v[2]), f2bf(v[3])};
                    *(short4*)(Kb + ((size_t)(b * NH + h) * HW + sp) * DH + dh0) = pk;
                } else {
                    const int c = o0 - 2 * HID, h = c >> 5, dh0 = c & 31;
                    #pragma unroll
                    for (int r = 0; r < 4; ++r)
                        Vb[((size_t)(b * NH + h) * DH + dh0 + r) * HW + s] = f2bf(v[r]);
                }
            } else {
                #pragma unroll
                for (int r = 0; r < 4; ++r)
                    out0[((size_t)b * NC + o0 + r) * HW + s] = v[r];
            }
        }
    }

    #pragma unroll
    for (int off = 32; off > 0; off >>= 1) e += __shfl_down(e, off);
    if (lane == 0) red[w] = e;
    __syncthreads();
    if (t == 0) {
        atomicAdd(E, red[0] + red[1] + red[2] + red[3]);
        if (!QKV) {
            __threadfence();
            const int prev = atomicAdd(ticket, 1);
            if (prev == nblocks - 1) {
                __threadfence();
                edst[0] = atomicAdd(E, 0.f);
            }
        }
    }
}

// ---------------------------------------------------------------------------
// Flash attention v9: flash7 inner loop + 2-way key split with WAIT-FREE
// atomic merge. Grid (36, 32): blockIdx.x = qt*2 + kh; block = 128 q x 4
// waves; keys [kh*1152, +1152), 18 iterations x 64 keys. m=0 fixed shift =>
// O, l, T are plain sums: each block atomicAdds fp32 partials into attO/L/T
// and exits (no flags, no spinning). Single P buffer per wave (LDS 26KB ->
// 6 blocks/CU capacity; grid 4.5/CU fully resident).
// ---------------------------------------------------------------------------
__global__ __launch_bounds__(256)
void flash9(const short* __restrict__ Qb, const short* __restrict__ Kb,
            const short* __restrict__ Vb, float* __restrict__ attO,
            float* __restrict__ Lb, float* __restrict__ Tb)
{
    __shared__ __align__(16) char smem[16384 + 4 * 2560];
    // [0,16384): KV buffers: parity p at p*8192, chunk ca at +ca*4096
    // [16384,+): per-wave P tile (32 rows x 40 shorts), reused across chunks

    const int qt   = blockIdx.x >> 1, kh = blockIdx.x & 1;
    const int bh   = blockIdx.y;
    const int w    = threadIdx.x >> 6;
    const int lane = threadIdx.x & 63;
    const int n16  = lane & 15, quad = lane >> 4;
    const int qb   = qt * 128 + w * 32;

    bf16x8 aq[2];
    #pragma unroll
    for (int qg = 0; qg < 2; ++qg)
        aq[qg] = *(const bf16x8*)(Qb + ((size_t)bh * HW + qb + qg * 16 + n16) * DH + quad * 8);

    // DMA role: waves 0,1 -> K halves; waves 2,3 -> V halves.
    const int rL = lane >> 2, cL = (lane & 3) ^ (rL & 3);
    const int kbeg = kh * KHALF;
    const char* gbase; size_t gstep;
    if (w < 2) {
        gbase = (const char*)(Kb + ((size_t)bh * HW + kbeg) * DH)
              + ((w & 1) * 16 + rL) * 64 + cL * 16;
        gstep = 2048;                      // 32 keys * 64 B
    } else {
        gbase = (const char*)(Vb + (size_t)bh * DH * HW + kbeg)
              + (size_t)((w & 1) * 16 + rL) * (HW * 2) + cL * 16;
        gstep = 64;                        // 32 keys * 2 B per dh-row
    }

    gld16(gbase,         smem + 0    + w * 1024);   // preload iteration 0
    gld16(gbase + gstep, smem + 4096 + w * 1024);

    f32x4 acc[2][2] = {};
    float ls[2][4] = {}, ts[2][4] = {};
    const int swz = (quad ^ (n16 & 3)) * 8;
    short* Ps = (short*)(smem + 16384) + w * 1280;
    unsigned* P32 = (unsigned*)Ps;

    for (int it = 0; it < NIT; ++it) {
        const int p = it & 1;
        __syncthreads();
        if (it + 1 < NIT) {
            const size_t g0 = (size_t)(2 * it + 2) * gstep;
            gld16(gbase + g0,         smem + (p ^ 1) * 8192 + 0    + w * 1024);
            gld16(gbase + g0 + gstep, smem + (p ^ 1) * 8192 + 4096 + w * 1024);
        }

        #pragma unroll
        for (int ca = 0; ca < 2; ++ca) {
            const short* kb = (const short*)(smem + p * 8192 + ca * 4096);

            const bf16x8 bk0 = *(const bf16x8*)(kb + n16 * 32 + swz);
            const bf16x8 bk1 = *(const bf16x8*)(kb + 512  + n16 * 32 + swz);
            const bf16x8 bv0 = *(const bf16x8*)(kb + 1024 + n16 * 32 + swz);
            const bf16x8 bv1 = *(const bf16x8*)(kb + 1536 + n16 * 32 + swz);

            #pragma unroll
            for (int qg = 0; qg < 2; ++qg) {
                f32x4 z = {};
                const f32x4 s0 = __builtin_amdgcn_mfma_f32_16x16x32_bf16(aq[qg], bk0, z, 0, 0, 0);
                const f32x4 s1 = __builtin_amdgcn_mfma_f32_16x16x32_bf16(aq[qg], bk1, z, 0, 0, 0);
                #pragma unroll
                for (int r = 0; r < 4; ++r) {
                    const float p0 = __builtin_amdgcn_exp2f(s0[r]);
                    const float p1 = __builtin_amdgcn_exp2f(s1[r]);
                    ls[qg][r] += p0 + p1;
                    ts[qg][r] += p0 * s0[r] + p1 * s1[r];
                    P32[(qg * 16 + quad * 4 + r) * 20 + n16] = pk2bf(p0, p1);
                }
            }
            #pragma unroll
            for (int qg = 0; qg < 2; ++qg) {
                const bf16x8 pa = *(const bf16x8*)(Ps + (qg * 16 + n16) * 40 + quad * 8);
                acc[qg][0] = __builtin_amdgcn_mfma_f32_16x16x32_bf16(pa, bv0, acc[qg][0], 0, 0, 0);
                acc[qg][1] = __builtin_amdgcn_mfma_f32_16x16x32_bf16(pa, bv1, acc[qg][1], 0, 0, 0);
            }
        }
    }

    // reduce ls/ts across the 16 key-lanes of each quad group
    #pragma unroll
    for (int m = 1; m < 16; m <<= 1)
        #pragma unroll
        for (int qg = 0; qg < 2; ++qg)
            #pragma unroll
            for (int r = 0; r < 4; ++r) {
                ls[qg][r] += __shfl_xor(ls[qg][r], m);
                ts[qg][r] += __shfl_xor(ts[qg][r], m);
            }

    // wait-free merge: plain device-scope atomic adds, then exit
    const int bb = bh >> 2, h = bh & 3;
    #pragma unroll
    for (int qg = 0; qg < 2; ++qg)
        #pragma unroll
        for (int r = 0; r < 4; ++r) {
            const int q = qb + qg * 16 + quad * 4 + r;
            float* op = attO + ((size_t)bb * HW + q) * HID + h * 32;
            atomicAdd(op + n16,      acc[qg][0][r]);
            atomicAdd(op + n16 + 16, acc[qg][1][r]);
        }
    if (n16 == 0) {
        #pragma unroll
        for (int qg = 0; qg < 2; ++qg)
            #pragma unroll
            for (int r = 0; r < 4; ++r) {
                const int q = qb + qg * 16 + quad * 4 + r;
                atomicAdd(&Lb[(size_t)bh * HW + q], ls[qg][r]);
                atomicAdd(&Tb[(size_t)bh * HW + q], ts[qg][r]);
            }
    }
}

// ---------------------------------------------------------------------------
// Normalize pass: attT[b][s][hid] = attO/L (bf16), e_attn = sum LN2*T/L-logL.
// Block = 16 s-rows x 128 hid; thread = (row, 8-dh chunk).
// ---------------------------------------------------------------------------
__global__ __launch_bounds__(256)
void norm_att(const float* __restrict__ attO, const float* __restrict__ Lb,
              const float* __restrict__ Tb, short* __restrict__ attT,
              float* __restrict__ E)
{
    __shared__ float red[4];
    const int b  = blockIdx.y;
    const int s  = blockIdx.x * 16 + (threadIdx.x >> 4);
    const int c0 = (threadIdx.x & 15) * 8;
    const int h  = c0 >> 5;

    const float L = Lb[((size_t)(b * NH + h)) * HW + s];
    const float invl = 1.f / L;
    const float* op = attO + ((size_t)b * HW + s) * HID + c0;
    const float4 v0 = *(const float4*)(op);
    const float4 v1 = *(const float4*)(op + 4);
    unsigned* ap = (unsigned*)(attT + ((size_t)b * HW + s) * HID + c0);
    ap[0] = pk2bf(v0.x * invl, v0.y * invl);
    ap[1] = pk2bf(v0.z * invl, v0.w * invl);
    ap[2] = pk2bf(v1.x * invl, v1.y * invl);
    ap[3] = pk2bf(v1.z * invl, v1.w * invl);

    float e = 0.f;
    if ((c0 & 31) == 0) {                    // one thread per (s, h)
        const float T = Tb[((size_t)(b * NH + h)) * HW + s];
        e = (LN2 * T) * invl - __logf(L);
    }
    #pragma unroll
    for (int off = 32; off > 0; off >>= 1) e += __shfl_down(e, off);
    const int lane = threadIdx.x & 63;
    if (lane == 0) red[threadIdx.x >> 6] = e;
    __syncthreads();
    if (threadIdx.x == 0) atomicAdd(E, red[0] + red[1] + red[2] + red[3]);
}

// ---------------------------------------------------------------------------
extern "C" void kernel_launch(void* const* d_in, const int* in_sizes, int n_in,
                              void* d_out, int out_size, void* d_ws, size_t ws_size,
                              hipStream_t stream) {
    const float* x     = (const float*)d_in[0];
    const float* w_qkv = (const float*)d_in[1];
    const float* b_qkv = (const float*)d_in[2];
    const float* w_out = (const float*)d_in[3];
    const float* b_out = (const float*)d_in[4];
    float* out = (float*)d_out;

    float* wsf    = (float*)d_ws;
    float* E      = wsf;                               // [0] energy accumulator
    int*   ticket = (int*)d_ws + 1;                    // [1] conv2 ticket
    short* Wq   = (short*)(wsf + 16);                  // bf16 [384][256]
    short* Wo   = Wq + 384 * 256;                      // bf16 [256][128]
    short* Xt   = Wo + 256 * 128;                      // bf16 [b][s][c]
    short* Qb   = Xt + (size_t)NB * HW * NC;           // bf16 [bh][s][dh] (xSCALE*log2e)
    short* Kb   = Qb + (size_t)NB * NH * HW * DH;      // bf16 [bh][s'][dh], pair-perm
    short* Vb   = Kb + (size_t)NB * NH * HW * DH;      // bf16 [bh][dh][s]
    short* attT = Vb + (size_t)NB * NH * HW * DH;      // bf16 [b][s][hid]
    float* attO = (float*)(attT + (size_t)NB * HW * HID);  // fp32 [b][s][hid]
    float* Lb   = attO + (size_t)NB * HW * HID;        // fp32 [bh][s]
    float* Tb   = Lb + (size_t)NB * NH * HW;           // fp32 [bh][s]

    const size_t zbytes = ((size_t)NB * HW * HID + 2 * (size_t)NB * NH * HW) * 4;
    (void)hipMemsetAsync(attO, 0, zbytes, stream);     // zero attO/L/T

    prep<<<dim3(HW / 32, NC / 32, NB + 1), 256, 0, stream>>>(
        x, w_qkv, w_out, Xt, Wq, Wo, wsf);
    conv_mfma<NC, true><<<dim3(18, 6, NB), 256, 0, stream>>>(
        Wq, Xt, b_qkv, nullptr, Qb, Kb, Vb, E, nullptr, 0, nullptr);
    flash9<<<dim3(NQT * KSPL, NB * NH), 256, 0, stream>>>(
        Qb, Kb, Vb, attO, Lb, Tb);
    norm_att<<<dim3(HW / 16, NB), 256, 0, stream>>>(
        attO, Lb, Tb, attT, E);
    conv_mfma<HID, false><<<dim3(18, 4, NB), 256, 0, stream>>>(
        Wo, attT, b_out, out, nullptr, nullptr, nullptr, E,
        ticket, 18 * 4 * NB, out + (size_t)NB * NC * HW);
}